// Round 11
// baseline (31767.255 us; speedup 1.0000x reference)
//
#include <hip/hip_runtime.h>
#include <math.h>

#define DM   1024
#define BSZ  4
#define LSEQ 4096
#define GPB  32            // WGs per batch group (co-resident on one XCD)
#define RPW  32            // rows per WG (DM / GPB)
#define TPB  512
#define SEGC 64            // columns per thread segment
#define SSP  68            // padded words per 64-col segment
#define HSW2 1088          // 16 * SSP : staged words per h buffer
#define XSW  1088          // padded words per x buffer
#define CRS  1092          // B row stride words in LDS

typedef unsigned long long u64;

__device__ __forceinline__ unsigned tg(u64 v) { return (unsigned)(v >> 32); }

// fast-copy read: RMW executes at the XCD L2 (non-blocking issue; compiler
// defers the waitcnt to first use of the result)
__device__ __forceinline__ u64 rmw(u64* p)
{
    return __hip_atomic_fetch_add(p, 0ULL, __ATOMIC_RELAXED,
                                  __HIP_MEMORY_SCOPE_WORKGROUP);
}
__device__ __forceinline__ u64 sload(u64* p)
{
    return __hip_atomic_load(p, __ATOMIC_RELAXED, __HIP_MEMORY_SCOPE_AGENT);
}

// fast tanh: (e^{2x}-1)/(e^{2x}+1); correct saturation via exp overflow
__device__ __forceinline__ float fast_tanh(float x)
{
    float e = __expf(2.0f * x);
    return (e - 1.0f) / (e + 1.0f);
}

// -------- Fused scan with in-shadow input projection (NO separate GEMM) ----
// 256 WGs; r=blockIdx&7: r<4 -> batch group r (32 WGs on XCD r under
// round-robin dispatch), r>=4 -> exit. 512 threads: row=t>>4, seg=t&15.
// A,C row-slices in regs (64 floats each); B row-slice in LDS (128KB);
// x double-buffered in LDS (staged 2 f32/thread at the step barrier).
// Exchange protocol = R8 verbatim: (tag<<32|float) u64 dual copy
// (fast: wg-scope store/RMW -> XCD L2; safe: agent scope -> MALL fallback),
// __syncthreads() barrier (vmcnt drain is load-bearing: producers' stores
// complete before the next poll cycle -- R10 proved removing it costs 3x).
// Per step k: poll s_k -> stage h + stage x_{k+1} -> barrier -> fused A+C
// matvec -> reduce A -> tanh(accA + bxv) -> dual h-store -> spec RMWs ->
// xv prefetch -> deferred: reduce C + y-store, B-dot over x_{k+1} -> bxv.
__global__ __launch_bounds__(TPB, 2) void scan_kernel(
    const float* __restrict__ A, const float* __restrict__ Cw,
    const float* __restrict__ Bw, const float* __restrict__ Dv,
    const float* __restrict__ X, float* __restrict__ Y,
    u64* hfast, u64* hsafe)
{
    const int r = blockIdx.x & 7;
    if (r >= BSZ) return;                    // 128 WGs exit immediately
    const int b  = r;                        // batch group
    const int gw = blockIdx.x >> 3;          // 0..31 within group
    const int r0 = gw * RPW;

    extern __shared__ float lds[];           // [RPW*CRS] B | 2*[HSW2] h | 2*[XSW] x
    float* bsl = lds;
    float* hs0 = lds + RPW * CRS;
    float* xs0 = hs0 + 2 * HSW2;
    const int t   = threadIdx.x;
    const int row = t >> 4;                  // 0..31
    const int seg = t & 15;                  // 64-col segment
    const bool lead = (seg == 0);

    // A and C row-slices -> registers (64 floats each)
    float ra[SEGC], rc[SEGC];
    {
        const float* Ap = A  + (size_t)(r0 + row) * DM + seg * SEGC;
        const float* Cp = Cw + (size_t)(r0 + row) * DM + seg * SEGC;
        #pragma unroll
        for (int u = 0; u < SEGC / 4; ++u) {
            float4 v = *(const float4*)(Ap + u*4);
            ra[u*4+0]=v.x; ra[u*4+1]=v.y; ra[u*4+2]=v.z; ra[u*4+3]=v.w;
            float4 w = *(const float4*)(Cp + u*4);
            rc[u*4+0]=w.x; rc[u*4+1]=w.y; rc[u*4+2]=w.z; rc[u*4+3]=w.w;
        }
    }
    // B row-slice -> LDS (coalesced, padded layout; reads are shadow-phase)
    for (int i = 0; i < 16; ++i) {
        int idx = i * TPB + t;               // float4 index, 8192 total
        int rr  = idx >> 8;
        int c4  = idx & 255;
        float4 v = *(const float4*)(Bw + (size_t)(r0 + rr) * DM + c4 * 4);
        *(float4*)(bsl + rr * CRS + (c4 >> 4) * SSP + (c4 & 15) * 4) = v;
    }
    const float dv = Dv[r0 + row];

    const int c0 = t, c1 = t + 512;
    const int s0 = (c0 >> 6) * SSP + (c0 & 63);
    const int s1 = (c1 >> 6) * SSP + (c1 & 63);
    const int xw = ((2*t) >> 6) * SSP + ((2*t) & 63);   // x-stage slot (float2)
    int fastok = 1;

    // ---- prologue: stage x_0, compute bx_0 in-kernel ----
    {
        float2 x0 = *(const float2*)(X + (size_t)b*LSEQ*DM + 2*t);
        *(float2*)(xs0 + xw) = x0;           // x_0 -> parity 0
    }
    // prologue spec for k=0: SAFE copy only (freshly memset through MALL)
    u64 v0 = sload(hsafe + (size_t)b * DM + c0);
    u64 v1 = sload(hsafe + (size_t)b * DM + c1);
    // prefetch x_1 for staging at iter 0
    float2 xr = make_float2(0.f, 0.f);
    if (1 < LSEQ)
        xr = *(const float2*)(X + (size_t)b*LSEQ*DM + (size_t)1*DM + 2*t);
    __syncthreads();
    float bxv = 0.f;                          // bx_k (tanh input at iter k)
    {
        float accB = 0.f;
        const float4* x4p = (const float4*)(xs0 + seg * SSP);
        const float4* b4p = (const float4*)(bsl + row * CRS + seg * SSP);
        #pragma unroll
        for (int u = 0; u < SEGC / 4; ++u) {
            float4 x4 = x4p[u];
            float4 b4 = b4p[u];
            accB += b4.x*x4.x + b4.y*x4.y + b4.z*x4.z + b4.w*x4.w;
        }
        accB += __shfl_xor(accB, 1);
        accB += __shfl_xor(accB, 2);
        accB += __shfl_xor(accB, 4);
        accB += __shfl_xor(accB, 8);
        if (lead) bxv = accB;
    }
    float xv = 0.f;                           // x_{k-1}[r0+row] (y at iter k)

    for (int k = 0; k <= LSEQ; ++k) {
        const unsigned tag = (unsigned)k;
        const size_t slot = (size_t)(k & 1) * BSZ * DM + (size_t)b * DM;

        // ---- finish poll for s_k (spec RMWs issued last iteration) ----
        if (tg(v0) != tag || tg(v1) != tag) {
            if (k == 0 || !fastok) {
                int spins = 0;
                while ((tg(v0) != tag || tg(v1) != tag) && ++spins < (1 << 20)) {
                    if (tg(v0) != tag) v0 = sload(hsafe + slot + c0);
                    if (tg(v1) != tag) v1 = sload(hsafe + slot + c1);
                }
            } else {
                int i = 0;
                while ((tg(v0) != tag || tg(v1) != tag) && i < 32) {
                    if (tg(v0) != tag) v0 = rmw(hfast + slot + c0);
                    if (tg(v1) != tag) v1 = rmw(hfast + slot + c1);
                    ++i;
                }
                if (tg(v0) != tag || tg(v1) != tag) {      // placement fallback
                    int spins = 0;
                    while ((tg(v0) != tag || tg(v1) != tag) && ++spins < (1 << 20)) {
                        if (tg(v0) != tag) v0 = sload(hsafe + slot + c0);
                        if (tg(v1) != tag) v1 = sload(hsafe + slot + c1);
                    }
                    u64 f = rmw(hfast + slot + c0);
                    if (tg(f) != tag) fastok = 0;          // fast path dead
                }
            }
        }

        float* hsk = hs0 + (k & 1) * HSW2;
        hsk[s0] = __uint_as_float((unsigned)v0);
        hsk[s1] = __uint_as_float((unsigned)v1);
        float* xsk = xs0 + ((k + 1) & 1) * XSW;
        if (k + 1 < LSEQ)
            *(float2*)(xsk + xw) = xr;        // stage x_{k+1}
        __syncthreads();                      // proven barrier (drains vmcnt)

        // ---- fused A+C matvec: one pass over staged h ----
        float accA = 0.f, accC = 0.f;
        {
            const float4* h4p = (const float4*)(hsk + seg * SSP);
            #pragma unroll
            for (int u = 0; u < SEGC / 4; ++u) {
                float4 h4 = h4p[u];
                accA += ra[u*4+0]*h4.x + ra[u*4+1]*h4.y + ra[u*4+2]*h4.z + ra[u*4+3]*h4.w;
                accC += rc[u*4+0]*h4.x + rc[u*4+1]*h4.y + rc[u*4+2]*h4.z + rc[u*4+3]*h4.w;
            }
        }

        float xv_next = xv;
        const size_t nslot = (size_t)((k+1) & 1) * BSZ * DM + (size_t)b * DM;
        if (k < LSEQ) {
            // ---- critical path: reduce accA, tanh, dual h-store ----
            accA += __shfl_xor(accA, 1);
            accA += __shfl_xor(accA, 2);
            accA += __shfl_xor(accA, 4);
            accA += __shfl_xor(accA, 8);
            if (lead) {
                float hv = fast_tanh(accA + bxv);
                u64 pk = ((u64)(unsigned)(k + 1) << 32) | (u64)__float_as_uint(hv);
                __hip_atomic_store(hfast + nslot + r0 + row, pk,
                                   __ATOMIC_RELAXED, __HIP_MEMORY_SCOPE_WORKGROUP);
                __hip_atomic_store(hsafe + nslot + r0 + row, pk,
                                   __ATOMIC_RELAXED, __HIP_MEMORY_SCOPE_AGENT);
            }
            // ---- issue speculative polls for step k+1 immediately ----
            if (fastok) {
                v0 = rmw(hfast + nslot + c0);
                v1 = rmw(hfast + nslot + c1);
            } else {
                v0 = sload(hsafe + nslot + c0);
                v1 = sload(hsafe + nslot + c1);
            }
            // prefetch operands (lead: x_k for y_k; all: x_{k+2} for staging)
            if (lead)
                xv_next = X[(size_t)b*LSEQ*DM + (size_t)k*DM + r0 + row];
            if (k + 2 < LSEQ)
                xr = *(const float2*)(X + (size_t)b*LSEQ*DM + (size_t)(k+2)*DM + 2*t);
        }

        // ---- deferred: reduce accC + y-store (off critical path) ----
        if (k > 0) {
            accC += __shfl_xor(accC, 1);
            accC += __shfl_xor(accC, 2);
            accC += __shfl_xor(accC, 4);
            accC += __shfl_xor(accC, 8);
            if (lead) {
                const size_t yoff = (size_t)b*LSEQ*DM + (size_t)(k-1)*DM + r0 + row;
                Y[yoff] = accC + dv * xv;        // y_{k-1} = C s_k + D x_{k-1}
            }
        }
        // ---- deferred: B-dot over x_{k+1} -> bx_{k+1} (shadow work) ----
        if (k + 1 < LSEQ) {
            float accB = 0.f;
            const float4* x4p = (const float4*)(xsk + seg * SSP);
            const float4* b4p = (const float4*)(bsl + row * CRS + seg * SSP);
            #pragma unroll
            for (int u = 0; u < SEGC / 4; ++u) {
                float4 x4 = x4p[u];
                float4 b4 = b4p[u];
                accB += b4.x*x4.x + b4.y*x4.y + b4.z*x4.z + b4.w*x4.w;
            }
            accB += __shfl_xor(accB, 1);
            accB += __shfl_xor(accB, 2);
            accB += __shfl_xor(accB, 4);
            accB += __shfl_xor(accB, 8);
            if (lead) bxv = accB;
        }
        xv = xv_next;
    }
}

extern "C" void kernel_launch(void* const* d_in, const int* in_sizes, int n_in,
                              void* d_out, int out_size, void* d_ws, size_t ws_size,
                              hipStream_t stream)
{
    const float* X  = (const float*)d_in[0];
    const float* A  = (const float*)d_in[1];
    const float* Bw = (const float*)d_in[2];
    const float* Cw = (const float*)d_in[3];
    const float* Dv = (const float*)d_in[4];
    float* Y    = (float*)d_out;
    u64* hfast  = (u64*)d_ws;
    u64* hsafe  = hfast + (size_t)2 * BSZ * DM;

    // zero both tagged copies every launch: (0.0f, tag 0) == s_0 ready
    hipMemsetAsync(d_ws, 0, (size_t)4 * BSZ * DM * sizeof(u64), stream);

    const size_t lds_bytes = (size_t)(RPW * CRS + 2 * HSW2 + 2 * XSW) * sizeof(float);
    scan_kernel<<<256, TPB, lds_bytes, stream>>>(A, Cw, Bw, Dv, X, Y, hfast, hsafe);
}

// Round 12
// 16648.428 us; speedup vs baseline: 1.9081x; 1.9081x over previous
//
#include <hip/hip_runtime.h>
#include <math.h>

#define DM   1024
#define BSZ  4
#define LSEQ 4096
#define GPB  32            // WGs per batch group (co-resident on one XCD)
#define RPW  32            // rows per WG (DM / GPB)
#define TPB  1024
#define SEGC 32            // columns per thread segment
#define SSP  68            // padded words per 64-col block
#define HSW2 1088          // 16 * SSP : staged words per h buffer

typedef unsigned long long u64;

// ---------------- Phase 1: bx = x @ B_w^T (fp32 NT GEMM) ----------------
__global__ __launch_bounds__(256) void bx_gemm_kernel(
    const float* __restrict__ X, const float* __restrict__ Bw,
    float* __restrict__ out)
{
    __shared__ float xs[16][68];
    __shared__ float bs[16][68];
    const int bm = blockIdx.x, bn = blockIdx.y;
    const int t  = threadIdx.x;
    const int tx = t & 15, ty = t >> 4;
    const int ml = t >> 2;
    const int kq = (t & 3) * 4;
    const float* xg = X  + (size_t)(bm * 64 + ml) * DM + kq;
    const float* bg = Bw + (size_t)(bn * 64 + ml) * DM + kq;
    float acc[4][4] = {};
    for (int k0 = 0; k0 < DM; k0 += 16) {
        float4 xv = *(const float4*)(xg + k0);
        float4 bv = *(const float4*)(bg + k0);
        __syncthreads();
        xs[kq+0][ml] = xv.x; xs[kq+1][ml] = xv.y; xs[kq+2][ml] = xv.z; xs[kq+3][ml] = xv.w;
        bs[kq+0][ml] = bv.x; bs[kq+1][ml] = bv.y; bs[kq+2][ml] = bv.z; bs[kq+3][ml] = bv.w;
        __syncthreads();
        #pragma unroll
        for (int kk = 0; kk < 16; ++kk) {
            float a[4], c[4];
            #pragma unroll
            for (int i = 0; i < 4; ++i) a[i] = xs[kk][ty*4+i];
            #pragma unroll
            for (int j = 0; j < 4; ++j) c[j] = bs[kk][tx*4+j];
            #pragma unroll
            for (int i = 0; i < 4; ++i)
                #pragma unroll
                for (int j = 0; j < 4; ++j)
                    acc[i][j] += a[i] * c[j];
        }
    }
    #pragma unroll
    for (int i = 0; i < 4; ++i) {
        float4 v = make_float4(acc[i][0], acc[i][1], acc[i][2], acc[i][3]);
        *(float4*)(out + (size_t)(bm*64 + ty*4 + i)*DM + bn*64 + tx*4) = v;
    }
}

__device__ __forceinline__ unsigned tg(u64 v) { return (unsigned)(v >> 32); }

// fast-copy read: RMW executes at the XCD L2 (non-blocking issue; compiler
// defers the waitcnt to first use of the result)
__device__ __forceinline__ u64 rmw(u64* p)
{
    return __hip_atomic_fetch_add(p, 0ULL, __ATOMIC_RELAXED,
                                  __HIP_MEMORY_SCOPE_WORKGROUP);
}
__device__ __forceinline__ u64 sload(u64* p)
{
    return __hip_atomic_load(p, __ATOMIC_RELAXED, __HIP_MEMORY_SCOPE_AGENT);
}

// fast tanh: (e^{2x}-1)/(e^{2x}+1); correct saturation via exp overflow
__device__ __forceinline__ float fast_tanh(float x)
{
    float e = __expf(2.0f * x);
    return (e - 1.0f) / (e + 1.0f);
}

// ---------------- Phase 2: fused scan, XCD-local tagged exchange ----------
// R8 protocol verbatim; only the thread geometry changed (TPB 512 -> 1024):
// each thread polls ONE tagged word, owns 32 A/C columns (ra[32], rc[32]),
// rows have 32 lanes (shfl chain 1,2,4,8,16). 256 WGs; r=blockIdx&7: r<4 ->
// batch group r (32 WGs on XCD r under round-robin dispatch), r>=4 -> exit.
// State = (tag<<32|float) u64 dual copy: fast (wg-scope store / RMW read ->
// XCD L2) + safe (agent scope -> MALL; k=0 prologue + placement fallback).
// __syncthreads() kept verbatim: its vmcnt drain is load-bearing (R10: the
// lgkm-only barrier cost 3x -- producers' stores must complete before the
// group's next poll cycle).
__global__ __launch_bounds__(TPB, 4) void scan_kernel(
    const float* __restrict__ A, const float* __restrict__ Cw,
    const float* __restrict__ Dv, const float* __restrict__ X,
    float* __restrict__ Y, u64* hfast, u64* hsafe)
{
    const int r = blockIdx.x & 7;
    if (r >= BSZ) return;                    // 128 WGs exit immediately
    const int b  = r;                        // batch group
    const int gw = blockIdx.x >> 3;          // 0..31 within group
    const int r0 = gw * RPW;

    __shared__ float hs0[2 * HSW2];          // staged h, double-buffered
    const int t   = threadIdx.x;
    const int row = t >> 5;                  // 0..31
    const int seg = t & 31;                  // 32-col segment
    const bool lead = (seg == 0);

    // A and C row-slices -> registers (32 floats each)
    float ra[SEGC], rc[SEGC];
    {
        const float* Ap = A  + (size_t)(r0 + row) * DM + seg * SEGC;
        const float* Cp = Cw + (size_t)(r0 + row) * DM + seg * SEGC;
        #pragma unroll
        for (int u = 0; u < SEGC / 4; ++u) {
            float4 v = *(const float4*)(Ap + u*4);
            ra[u*4+0]=v.x; ra[u*4+1]=v.y; ra[u*4+2]=v.z; ra[u*4+3]=v.w;
            float4 w = *(const float4*)(Cp + u*4);
            rc[u*4+0]=w.x; rc[u*4+1]=w.y; rc[u*4+2]=w.z; rc[u*4+3]=w.w;
        }
    }
    const float dv = Dv[r0 + row];

    const int c0 = t;                                   // single polled word
    const int s0 = (t >> 6) * SSP + (t & 63);           // staging slot
    const int hb = (seg >> 1) * SSP + (seg & 1) * 32;   // matvec read base
    int fastok = 1;

    // prologue spec for k=0: SAFE copy only (freshly memset through MALL;
    // stale fast lines cannot alias: kernel-boundary L2 flush + 2-slot ABA)
    u64 v0 = sload(hsafe + (size_t)b * DM + c0);
    float bxv = 0.f;          // bx_k    (tanh input at iteration k)
    float xv  = 0.f;          // x_{k-1} (y-store at iteration k)
    if (lead) bxv = Y[(size_t)b*LSEQ*DM + r0 + row];

    for (int k = 0; k <= LSEQ; ++k) {
        const unsigned tag = (unsigned)k;
        const size_t slot = (size_t)(k & 1) * BSZ * DM + (size_t)b * DM;

        // ---- finish poll for s_k (spec RMW issued last iteration) ----
        if (tg(v0) != tag) {
            if (k == 0 || !fastok) {
                int spins = 0;
                do {
                    v0 = sload(hsafe + slot + c0);
                } while (tg(v0) != tag && ++spins < (1 << 20));
            } else {
                int i = 0;
                while (tg(v0) != tag && i < 32) { v0 = rmw(hfast + slot + c0); ++i; }
                if (tg(v0) != tag) {                       // placement fallback
                    int spins = 0;
                    do {
                        v0 = sload(hsafe + slot + c0);
                    } while (tg(v0) != tag && ++spins < (1 << 20));
                    u64 f = rmw(hfast + slot + c0);
                    if (tg(f) != tag) fastok = 0;          // fast path dead
                }
            }
        }

        float* hsk = hs0 + (k & 1) * HSW2;
        hsk[s0] = __uint_as_float((unsigned)v0);
        __syncthreads();   // proven barrier (vmcnt drain is load-bearing)

        // ---- fused A+C matvec: one pass over this thread's 32 cols ----
        float accA = 0.f, accC = 0.f;
        {
            const float4* h4p = (const float4*)(hsk + hb);
            #pragma unroll
            for (int u = 0; u < SEGC / 4; ++u) {
                float4 h4 = h4p[u];
                accA += ra[u*4+0]*h4.x + ra[u*4+1]*h4.y + ra[u*4+2]*h4.z + ra[u*4+3]*h4.w;
                accC += rc[u*4+0]*h4.x + rc[u*4+1]*h4.y + rc[u*4+2]*h4.z + rc[u*4+3]*h4.w;
            }
        }

        float xv_next = xv;
        const size_t nslot = (size_t)((k+1) & 1) * BSZ * DM + (size_t)b * DM;
        if (k < LSEQ) {
            // ---- critical path: reduce accA, tanh, dual h-store ----
            accA += __shfl_xor(accA, 1);
            accA += __shfl_xor(accA, 2);
            accA += __shfl_xor(accA, 4);
            accA += __shfl_xor(accA, 8);
            accA += __shfl_xor(accA, 16);
            if (lead) {
                float hv = fast_tanh(accA + bxv);
                u64 pk = ((u64)(unsigned)(k + 1) << 32) | (u64)__float_as_uint(hv);
                __hip_atomic_store(hfast + nslot + r0 + row, pk,
                                   __ATOMIC_RELAXED, __HIP_MEMORY_SCOPE_WORKGROUP);
                __hip_atomic_store(hsafe + nslot + r0 + row, pk,
                                   __ATOMIC_RELAXED, __HIP_MEMORY_SCOPE_AGENT);
            }
            // ---- issue speculative poll for step k+1 immediately ----
            if (fastok) v0 = rmw(hfast + nslot + c0);
            else        v0 = sload(hsafe + nslot + c0);
            // prefetch next-step operands (lead lanes only)
            if (lead) {
                xv_next = X[(size_t)b*LSEQ*DM + (size_t)k*DM + r0 + row];   // x_k
                if (k + 1 < LSEQ)
                    bxv = Y[(size_t)b*LSEQ*DM + (size_t)(k+1)*DM + r0 + row];
            }
        }

        // ---- deferred: reduce accC + y-store (off critical path) ----
        if (k > 0) {
            accC += __shfl_xor(accC, 1);
            accC += __shfl_xor(accC, 2);
            accC += __shfl_xor(accC, 4);
            accC += __shfl_xor(accC, 8);
            accC += __shfl_xor(accC, 16);
            if (lead) {
                const size_t yoff = (size_t)b*LSEQ*DM + (size_t)(k-1)*DM + r0 + row;
                Y[yoff] = accC + dv * xv;        // y_{k-1} = C s_k + D x_{k-1}
            }
        }
        xv = xv_next;
    }
}

extern "C" void kernel_launch(void* const* d_in, const int* in_sizes, int n_in,
                              void* d_out, int out_size, void* d_ws, size_t ws_size,
                              hipStream_t stream)
{
    const float* X  = (const float*)d_in[0];
    const float* A  = (const float*)d_in[1];
    const float* Bw = (const float*)d_in[2];
    const float* Cw = (const float*)d_in[3];
    const float* Dv = (const float*)d_in[4];
    float* Y    = (float*)d_out;
    u64* hfast  = (u64*)d_ws;
    u64* hsafe  = hfast + (size_t)2 * BSZ * DM;

    // zero both tagged copies every launch: (0.0f, tag 0) == s_0 ready
    hipMemsetAsync(d_ws, 0, (size_t)4 * BSZ * DM * sizeof(u64), stream);

    dim3 g1((BSZ * LSEQ) / 64, DM / 64);
    bx_gemm_kernel<<<g1, 256, 0, stream>>>(X, Bw, Y);
    scan_kernel<<<256, TPB, 0, stream>>>(A, Cw, Dv, X, Y, hfast, hsafe);
}